// Round 10
// baseline (1713.668 us; speedup 1.0000x reference)
//
#include <hip/hip_runtime.h>

// RandomHingeForest forward
// x:          [8192, 1024]  f32
// thresholds: [1024, 1023]  f32   (heap layout, children 2i+1 / 2i+2)
// ordinals:   [1024, 1023]  i32
// weights:    [1024, 1024, 16] f32
// out:        [8192, 1024, 16] f32 = min|x[ord]-thr| along path * leaf weights
//
// Layout: packed node-major records pk[node][tree] = {thr, ord} (float2,
// built in d_ws each launch). Wave lanes = consecutive trees, so shallow
// levels coalesce and packing halves scattered-transaction count deep.
// Round 6: nontemporal loads on the scattered walk/weight gathers
// (bypass L1 — deep-level lines have no L1 reuse and the 64-line-per-gather
// fill demand thrashes L1 MSHRs, serializing all resident waves), and
// nontemporal stores for the 512 MiB output stream (don't evict L2).

#define BATCH    8192
#define IN_CH    1024
#define TREES    1024
#define N_NODES  1023
#define N_LEAVES 1024
#define DEPTH    10
#define EXTRA    16
#define TPB      256
#define BPB      2          // batch samples (chains) per thread

typedef float f2v __attribute__((ext_vector_type(2)));
typedef float f4v __attribute__((ext_vector_type(4)));

// ---------------- prep: pk[n][t] = {thr[t][n], bits(ord[t][n])} -------------
__global__ __launch_bounds__(TPB) void pack_nodes_kernel(
    const float* __restrict__ thr, const int* __restrict__ ord,
    f2v* __restrict__ pk) {
  int i = blockIdx.x * TPB + threadIdx.x;          // i = n*TREES + t
  if (i >= TREES * N_NODES) return;
  int n = i / TREES;
  int t = i - n * TREES;
  f2v r;
  r[0] = thr[(size_t)t * N_NODES + n];
  r[1] = __int_as_float(ord[(size_t)t * N_NODES + n]);
  pk[i] = r;
}

// ---------------- main walk: 2 samples x 1 tree per thread ------------------
__global__ __launch_bounds__(TPB, 8) void hinge_forest_kernel(
    const float* __restrict__ x,
    const f2v* __restrict__ pk,
    const float* __restrict__ w,
    float*       __restrict__ out) {
  __shared__ float xrow[BPB][IN_CH];

  const int b0 = blockIdx.y * BPB;
  const int t  = blockIdx.x * TPB + threadIdx.x;

  // Stage BPB x-rows (4 KiB each) into LDS, coalesced float4.
#pragma unroll
  for (int r = 0; r < BPB; ++r) {
    reinterpret_cast<float4*>(xrow[r])[threadIdx.x] =
        reinterpret_cast<const float4*>(x + (size_t)(b0 + r) * IN_CH)[threadIdx.x];
  }
  __syncthreads();

  int   n0 = 0, n1 = 0;
  float m0 = INFINITY, m1 = INFINITY;
#pragma unroll
  for (int d = 0; d < DEPTH; ++d) {
    // two independent 8 B gathers, L1-bypassed -> 2-deep MLP per thread
    const f2v a0 = __builtin_nontemporal_load(&pk[(size_t)n0 * TREES + t]);
    const f2v a1 = __builtin_nontemporal_load(&pk[(size_t)n1 * TREES + t]);
    const float g0 = xrow[0][__float_as_int(a0[1])] - a0[0];
    const float g1 = xrow[1][__float_as_int(a1[1])] - a1[0];
    m0 = fminf(m0, fabsf(g0));
    m1 = fminf(m1, fabsf(g1));
    n0 = 2 * n0 + 1 + (g0 > 0.0f);
    n1 = 2 * n1 + 1 + (g1 > 0.0f);
  }
  const int l0 = n0 - N_NODES;
  const int l1 = n1 - N_NODES;

  const f4v* w0 = reinterpret_cast<const f4v*>(
      w + ((size_t)t * N_LEAVES + l0) * EXTRA);
  const f4v* w1 = reinterpret_cast<const f4v*>(
      w + ((size_t)t * N_LEAVES + l1) * EXTRA);
  f4v* o0 = reinterpret_cast<f4v*>(
      out + ((size_t)b0 * TREES + t) * EXTRA);
  f4v* o1 = reinterpret_cast<f4v*>(
      out + ((size_t)(b0 + 1) * TREES + t) * EXTRA);
#pragma unroll
  for (int e = 0; e < 4; ++e) {
    const f4v wv0 = __builtin_nontemporal_load(&w0[e]);
    const f4v wv1 = __builtin_nontemporal_load(&w1[e]);
    __builtin_nontemporal_store(m0 * wv0, &o0[e]);
    __builtin_nontemporal_store(m1 * wv1, &o1[e]);
  }
}

// ---------------- fallback (ws too small): direct thr/ord reads -------------
__global__ __launch_bounds__(TPB, 8) void hinge_forest_fallback(
    const float* __restrict__ x,
    const float* __restrict__ thr,
    const int*   __restrict__ ord,
    const float* __restrict__ w,
    float*       __restrict__ out) {
  __shared__ float xrow[IN_CH];
  const int b = blockIdx.y;
  const int t = blockIdx.x * TPB + threadIdx.x;
  reinterpret_cast<float4*>(xrow)[threadIdx.x] =
      reinterpret_cast<const float4*>(x + (size_t)b * IN_CH)[threadIdx.x];
  __syncthreads();
  const float* tthr = thr + (size_t)t * N_NODES;
  const int*   tord = ord + (size_t)t * N_NODES;
  int node = 0; float mm = INFINITY;
#pragma unroll
  for (int d = 0; d < DEPTH; ++d) {
    const float th = tthr[node];
    const int   o  = tord[node];
    const float m  = xrow[o] - th;
    mm = fminf(mm, fabsf(m));
    node = 2 * node + 1 + (m > 0.0f);
  }
  const int leaf = node - N_NODES;
  const float4* wp = reinterpret_cast<const float4*>(
      w + ((size_t)t * N_LEAVES + leaf) * EXTRA);
  float4* op = reinterpret_cast<float4*>(
      out + ((size_t)b * TREES + t) * EXTRA);
#pragma unroll
  for (int e = 0; e < 4; ++e) {
    const float4 wv = wp[e];
    op[e] = make_float4(mm * wv.x, mm * wv.y, mm * wv.z, mm * wv.w);
  }
}

extern "C" void kernel_launch(void* const* d_in, const int* in_sizes, int n_in,
                              void* d_out, int out_size, void* d_ws, size_t ws_size,
                              hipStream_t stream) {
  const float* x   = (const float*)d_in[0];
  const float* thr = (const float*)d_in[1];
  const int*   ord = (const int*)d_in[2];
  const float* w   = (const float*)d_in[3];
  float*       out = (float*)d_out;

  const size_t pk_bytes = (size_t)TREES * N_NODES * sizeof(f2v);  // 8 MiB
  if (ws_size >= pk_bytes) {
    f2v* pk = (f2v*)d_ws;
    const int total = TREES * N_NODES;
    pack_nodes_kernel<<<(total + TPB - 1) / TPB, TPB, 0, stream>>>(thr, ord, pk);
    dim3 grid(TREES / TPB, BATCH / BPB);
    hinge_forest_kernel<<<grid, dim3(TPB, 1, 1), 0, stream>>>(x, pk, w, out);
  } else {
    dim3 grid(TREES / TPB, BATCH);
    hinge_forest_fallback<<<grid, dim3(TPB, 1, 1), 0, stream>>>(x, thr, ord, w, out);
  }
}

// Round 11
// 857.525 us; speedup vs baseline: 1.9984x; 1.9984x over previous
//
#include <hip/hip_runtime.h>

// RandomHingeForest forward
// x: [8192,1024] f32; thresholds/ordinals: [1024,1023] (heap layout);
// weights: [1024,1024,16] f32; out: [8192,1024,16] f32.
//
// Round 11: walk re-grouped into 3-level subtree records. One record = 7
// nodes {thr, ord} of a 3-level subtree, 56 B padded to 64 B = exactly one
// cache line, node-major rec[r][tree] in d_ws. Per chain: 4 record loads
// (levels 0-2, 3-5, 6-8, 9) instead of 10 scattered 8-B loads -> ~1.7x fewer
// L2/L3 transactions (the round-5/10 bottleneck) and a 4-deep (not 10-deep)
// dependent chain. Routing inside a record is cndmask selection (VALU ~6%
// busy, plenty of headroom). NO nontemporal anywhere (round 10: slc bypasses
// L2/L3 -> 3.2x regression).

#define BATCH    8192
#define IN_CH    1024
#define TREES    1024
#define N_NODES  1023
#define N_LEAVES 1024
#define EXTRA    16
#define TPB      256
#define BPB      2          // batch samples (chains) per thread

typedef float f2v __attribute__((ext_vector_type(2)));
typedef float f4v __attribute__((ext_vector_type(4)));

// d_ws layout (bytes): records for level-groups rooted at depth 0, 3, 6,
// then plain {thr,ord} pairs for depth 9.
#define G0_OFF   0u
#define G1_OFF   (G0_OFF + 1024u*64u)          // g0: 1 rec   x 1024 trees
#define G2_OFF   (G1_OFF + 8u*1024u*64u)       // g1: 8 recs  x 1024 trees
#define G3_OFF   (G2_OFF + 64u*1024u*64u)      // g2: 64 recs x 1024 trees
#define WS_NEED  (G3_OFF + 512u*1024u*8u)      // g3: 512 x 1024 x 8 B = 8978432 total
#define R5_NEED  (1024u*1023u*8u)              // round-5 fallback pk size

// ---- prep A: 3-level records. rec(g,r,t) = BFS nodes {h0; 2h0+1,2h0+2;
// 4h0+3..4h0+6} of tree t, h0 = (2^d0 - 1) + r. Stored as 4 x f4v:
// q0={n0,n1} q1={n2,n3} q2={n4,n5} q3={n6,pad}, each node = {thr, ord}.
__global__ __launch_bounds__(TPB) void prep_records(
    const float* __restrict__ thr, const int* __restrict__ ord,
    f4v* __restrict__ g0, f4v* __restrict__ g1, f4v* __restrict__ g2) {
  const int i = blockIdx.x * TPB + threadIdx.x;
  if (i >= 1024 + 8 * 1024 + 64 * 1024) return;
  int r, t, h0;
  f4v* dst;
  if (i < 1024) {
    r = 0; t = i; h0 = 0;
    dst = g0 + (size_t)t * 4;
  } else if (i < 9216) {
    const int j = i - 1024; r = j >> 10; t = j & 1023; h0 = 7 + r;
    dst = g1 + ((size_t)(r << 10) + t) * 4;
  } else {
    const int j = i - 9216; r = j >> 10; t = j & 1023; h0 = 63 + r;
    dst = g2 + ((size_t)(r << 10) + t) * 4;
  }
  const float* tt = thr + (size_t)t * N_NODES;
  const int*   to = ord + (size_t)t * N_NODES;
  const int h1 = 2 * h0 + 1, h2 = 2 * h0 + 2, h3 = 4 * h0 + 3;
  f4v q0, q1, q2, q3;
  q0[0] = tt[h0];     q0[1] = __int_as_float(to[h0]);
  q0[2] = tt[h1];     q0[3] = __int_as_float(to[h1]);
  q1[0] = tt[h2];     q1[1] = __int_as_float(to[h2]);
  q1[2] = tt[h3];     q1[3] = __int_as_float(to[h3]);
  q2[0] = tt[h3 + 1]; q2[1] = __int_as_float(to[h3 + 1]);
  q2[2] = tt[h3 + 2]; q2[3] = __int_as_float(to[h3 + 2]);
  q3[0] = tt[h3 + 3]; q3[1] = __int_as_float(to[h3 + 3]);
  q3[2] = 0.0f;       q3[3] = 0.0f;
  dst[0] = q0; dst[1] = q1; dst[2] = q2; dst[3] = q3;
}

// ---- prep B: depth-9 nodes as node-major {thr, ord} pairs. r in [0,512).
__global__ __launch_bounds__(TPB) void prep_level9(
    const float* __restrict__ thr, const int* __restrict__ ord,
    f2v* __restrict__ pk3) {
  const int i = blockIdx.x * TPB + threadIdx.x;   // i = r*1024 + t
  if (i >= 512 * 1024) return;
  const int r = i >> 10, t = i & 1023;
  const int h = 511 + r;
  f2v a;
  a[0] = thr[(size_t)t * N_NODES + h];
  a[1] = __int_as_float(ord[(size_t)t * N_NODES + h]);
  pk3[i] = a;
}

// ---- 3 levels through one preloaded record ------------------------------
__device__ __forceinline__ void step3(f4v q0, f4v q1, f4v q2, f4v q3,
                                      const float* __restrict__ xr,
                                      float& mm, int& r) {
  const float ga = xr[__float_as_int(q0[1])] - q0[0];
  mm = fminf(mm, fabsf(ga));
  const bool b0 = ga > 0.0f;
  const float th1 = b0 ? q1[0] : q0[2];
  const float o1  = b0 ? q1[1] : q0[3];
  const float gb = xr[__float_as_int(o1)] - th1;
  mm = fminf(mm, fabsf(gb));
  const bool b1 = gb > 0.0f;
  const float thA = b1 ? q2[0] : q1[2];
  const float oA  = b1 ? q2[1] : q1[3];
  const float thB = b1 ? q3[0] : q2[2];
  const float oB  = b1 ? q3[1] : q2[3];
  const float th2 = b0 ? thB : thA;
  const float o2  = b0 ? oB  : oA;
  const float gc = xr[__float_as_int(o2)] - th2;
  mm = fminf(mm, fabsf(gc));
  const bool b2 = gc > 0.0f;
  r = (r << 3) + (b0 ? 4 : 0) + (b1 ? 2 : 0) + (b2 ? 1 : 0);
}

// ---- main walk: 2 samples x 1 tree per thread ---------------------------
__global__ __launch_bounds__(TPB) void hinge_forest_kernel(
    const float* __restrict__ x,
    const f4v* __restrict__ g0, const f4v* __restrict__ g1,
    const f4v* __restrict__ g2, const f2v* __restrict__ pk3,
    const float* __restrict__ w, float* __restrict__ out) {
  __shared__ float xrow[BPB][IN_CH];

  const int bb = blockIdx.y * BPB;
  const int t  = blockIdx.x * TPB + threadIdx.x;

#pragma unroll
  for (int r = 0; r < BPB; ++r) {
    reinterpret_cast<float4*>(xrow[r])[threadIdx.x] =
        reinterpret_cast<const float4*>(x + (size_t)(bb + r) * IN_CH)[threadIdx.x];
  }
  __syncthreads();

  float m0 = INFINITY, m1 = INFINITY;
  int   r0 = 0, r1 = 0;

  {  // levels 0-2: both chains share tree t's single root record
    const f4v* p = g0 + (size_t)t * 4;
    const f4v a0 = p[0], a1 = p[1], a2 = p[2], a3 = p[3];
    step3(a0, a1, a2, a3, xrow[0], m0, r0);
    step3(a0, a1, a2, a3, xrow[1], m1, r1);
  }
  {  // levels 3-5
    const f4v* p0 = g1 + ((size_t)(r0 << 10) + t) * 4;
    const f4v* p1 = g1 + ((size_t)(r1 << 10) + t) * 4;
    const f4v a0 = p0[0], a1 = p0[1], a2 = p0[2], a3 = p0[3];
    const f4v c0 = p1[0], c1 = p1[1], c2 = p1[2], c3 = p1[3];
    step3(a0, a1, a2, a3, xrow[0], m0, r0);
    step3(c0, c1, c2, c3, xrow[1], m1, r1);
  }
  {  // levels 6-8
    const f4v* p0 = g2 + ((size_t)(r0 << 10) + t) * 4;
    const f4v* p1 = g2 + ((size_t)(r1 << 10) + t) * 4;
    const f4v a0 = p0[0], a1 = p0[1], a2 = p0[2], a3 = p0[3];
    const f4v c0 = p1[0], c1 = p1[1], c2 = p1[2], c3 = p1[3];
    step3(a0, a1, a2, a3, xrow[0], m0, r0);
    step3(c0, c1, c2, c3, xrow[1], m1, r1);
  }
  // level 9
  const f2v a = pk3[(r0 << 10) + t];
  const f2v c = pk3[(r1 << 10) + t];
  const float ga = xrow[0][__float_as_int(a[1])] - a[0];
  const float gc = xrow[1][__float_as_int(c[1])] - c[0];
  m0 = fminf(m0, fabsf(ga));
  m1 = fminf(m1, fabsf(gc));
  const int l0 = r0 * 2 + (ga > 0.0f);
  const int l1 = r1 * 2 + (gc > 0.0f);

  // epilogue: w gather (64 B/lane) + contiguous store (regular, cached)
  const float4* w0 = reinterpret_cast<const float4*>(
      w + ((size_t)t * N_LEAVES + l0) * EXTRA);
  const float4* w1 = reinterpret_cast<const float4*>(
      w + ((size_t)t * N_LEAVES + l1) * EXTRA);
  float4* o0 = reinterpret_cast<float4*>(
      out + ((size_t)bb * TREES + t) * EXTRA);
  float4* o1 = reinterpret_cast<float4*>(
      out + ((size_t)(bb + 1) * TREES + t) * EXTRA);
#pragma unroll
  for (int e = 0; e < 4; ++e) {
    const float4 wv0 = w0[e];
    const float4 wv1 = w1[e];
    o0[e] = make_float4(m0 * wv0.x, m0 * wv0.y, m0 * wv0.z, m0 * wv0.w);
    o1[e] = make_float4(m1 * wv1.x, m1 * wv1.y, m1 * wv1.z, m1 * wv1.w);
  }
}

// ---------------- round-5 fallback (ws >= 8 MiB but < 8.56 MiB) ----------
__global__ __launch_bounds__(TPB) void pack_nodes_kernel(
    const float* __restrict__ thr, const int* __restrict__ ord,
    f2v* __restrict__ pk) {
  int i = blockIdx.x * TPB + threadIdx.x;
  if (i >= TREES * N_NODES) return;
  int n = i / TREES;
  int t = i - n * TREES;
  f2v r;
  r[0] = thr[(size_t)t * N_NODES + n];
  r[1] = __int_as_float(ord[(size_t)t * N_NODES + n]);
  pk[i] = r;
}

__global__ __launch_bounds__(TPB) void hinge_forest_r5(
    const float* __restrict__ x, const f2v* __restrict__ pk,
    const float* __restrict__ w, float* __restrict__ out) {
  __shared__ float xrow[BPB][IN_CH];
  const int bb = blockIdx.y * BPB;
  const int t  = blockIdx.x * TPB + threadIdx.x;
#pragma unroll
  for (int r = 0; r < BPB; ++r) {
    reinterpret_cast<float4*>(xrow[r])[threadIdx.x] =
        reinterpret_cast<const float4*>(x + (size_t)(bb + r) * IN_CH)[threadIdx.x];
  }
  __syncthreads();
  int n0 = 0, n1 = 0;
  float m0 = INFINITY, m1 = INFINITY;
#pragma unroll
  for (int d = 0; d < 10; ++d) {
    const f2v a0 = pk[(size_t)n0 * TREES + t];
    const f2v a1 = pk[(size_t)n1 * TREES + t];
    const float ga = xrow[0][__float_as_int(a0[1])] - a0[0];
    const float gb = xrow[1][__float_as_int(a1[1])] - a1[0];
    m0 = fminf(m0, fabsf(ga));
    m1 = fminf(m1, fabsf(gb));
    n0 = 2 * n0 + 1 + (ga > 0.0f);
    n1 = 2 * n1 + 1 + (gb > 0.0f);
  }
  const int l0 = n0 - N_NODES, l1 = n1 - N_NODES;
  const float4* w0 = reinterpret_cast<const float4*>(
      w + ((size_t)t * N_LEAVES + l0) * EXTRA);
  const float4* w1 = reinterpret_cast<const float4*>(
      w + ((size_t)t * N_LEAVES + l1) * EXTRA);
  float4* o0 = reinterpret_cast<float4*>(out + ((size_t)bb * TREES + t) * EXTRA);
  float4* o1 = reinterpret_cast<float4*>(out + ((size_t)(bb + 1) * TREES + t) * EXTRA);
#pragma unroll
  for (int e = 0; e < 4; ++e) {
    const float4 wv0 = w0[e];
    const float4 wv1 = w1[e];
    o0[e] = make_float4(m0 * wv0.x, m0 * wv0.y, m0 * wv0.z, m0 * wv0.w);
    o1[e] = make_float4(m1 * wv1.x, m1 * wv1.y, m1 * wv1.z, m1 * wv1.w);
  }
}

// ---------------- direct fallback (tiny ws) ------------------------------
__global__ __launch_bounds__(TPB) void hinge_forest_direct(
    const float* __restrict__ x, const float* __restrict__ thr,
    const int* __restrict__ ord, const float* __restrict__ w,
    float* __restrict__ out) {
  __shared__ float xrow[IN_CH];
  const int b = blockIdx.y;
  const int t = blockIdx.x * TPB + threadIdx.x;
  reinterpret_cast<float4*>(xrow)[threadIdx.x] =
      reinterpret_cast<const float4*>(x + (size_t)b * IN_CH)[threadIdx.x];
  __syncthreads();
  const float* tt = thr + (size_t)t * N_NODES;
  const int*   to = ord + (size_t)t * N_NODES;
  int node = 0; float mm = INFINITY;
#pragma unroll
  for (int d = 0; d < 10; ++d) {
    const float th = tt[node];
    const int   o  = to[node];
    const float m  = xrow[o] - th;
    mm = fminf(mm, fabsf(m));
    node = 2 * node + 1 + (m > 0.0f);
  }
  const int leaf = node - N_NODES;
  const float4* wp = reinterpret_cast<const float4*>(
      w + ((size_t)t * N_LEAVES + leaf) * EXTRA);
  float4* op = reinterpret_cast<float4*>(out + ((size_t)b * TREES + t) * EXTRA);
#pragma unroll
  for (int e = 0; e < 4; ++e) {
    const float4 wv = wp[e];
    op[e] = make_float4(mm * wv.x, mm * wv.y, mm * wv.z, mm * wv.w);
  }
}

extern "C" void kernel_launch(void* const* d_in, const int* in_sizes, int n_in,
                              void* d_out, int out_size, void* d_ws, size_t ws_size,
                              hipStream_t stream) {
  const float* x   = (const float*)d_in[0];
  const float* thr = (const float*)d_in[1];
  const int*   ord = (const int*)d_in[2];
  const float* w   = (const float*)d_in[3];
  float*       out = (float*)d_out;

  if (ws_size >= WS_NEED) {
    char* wsb = (char*)d_ws;
    f4v* g0  = (f4v*)(wsb + G0_OFF);
    f4v* g1  = (f4v*)(wsb + G1_OFF);
    f4v* g2  = (f4v*)(wsb + G2_OFF);
    f2v* pk3 = (f2v*)(wsb + G3_OFF);
    const int nrec = 1024 + 8 * 1024 + 64 * 1024;
    prep_records<<<(nrec + TPB - 1) / TPB, TPB, 0, stream>>>(thr, ord, g0, g1, g2);
    prep_level9<<<(512 * 1024) / TPB, TPB, 0, stream>>>(thr, ord, pk3);
    dim3 grid(TREES / TPB, BATCH / BPB);
    hinge_forest_kernel<<<grid, dim3(TPB, 1, 1), 0, stream>>>(
        x, g0, g1, g2, pk3, w, out);
  } else if (ws_size >= R5_NEED) {
    f2v* pk = (f2v*)d_ws;
    pack_nodes_kernel<<<(TREES * N_NODES + TPB - 1) / TPB, TPB, 0, stream>>>(
        thr, ord, pk);
    dim3 grid(TREES / TPB, BATCH / BPB);
    hinge_forest_r5<<<grid, dim3(TPB, 1, 1), 0, stream>>>(x, pk, w, out);
  } else {
    dim3 grid(TREES / TPB, BATCH);
    hinge_forest_direct<<<grid, dim3(TPB, 1, 1), 0, stream>>>(x, thr, ord, w, out);
  }
}